// Round 11
// baseline (31226.733 us; speedup 1.0000x reference)
//
#include <hip/hip_runtime.h>

#define T_LEN 512
#define HID   64
#define NG    256   // 4*HID gate rows
#define B_TILE 4
#define NTHR  512

typedef float f4 __attribute__((ext_vector_type(4)));

__device__ __forceinline__ float sigm(float x)  { return 1.0f / (1.0f + __expf(-x)); }
__device__ __forceinline__ float tanh_f(float x){ float e = __expf(2.0f * x); return 1.0f - 2.0f / (e + 1.0f); }

#define REP8(M) M(0) M(1) M(2) M(3) M(4) M(5) M(6) M(7)

// Lane-pair row split: lanes l and l^32 each own half (32 weights) of gate row
// g = wave*32 + (lane&31); halves combine via one shfl_xor(32) — no barrier.
// Per-thread weights: 24 f4 = 96 VGPRs; peak live ~150.
// KEY CHANGE vs round 8: amdgpu_waves_per_eu(2,2) — BOTH bounds. Single-arg
// (min-only) and __launch_bounds__ were ignored: allocator picked its own
// occupancy (r1/3/8: 128 VGPR, r9: 64) and spilled the loop-invariant weights
// -> 40-85 GB/dispatch of scratch re-reads. (2,2) forces a 256-VGPR budget.
__global__ __attribute__((amdgpu_flat_work_group_size(NTHR, NTHR), amdgpu_waves_per_eu(2, 2)))
void lstm2_kernel(const float* __restrict__ x,
                  const float* __restrict__ Wih0, const float* __restrict__ Whh0,
                  const float* __restrict__ bih0, const float* __restrict__ bhh0,
                  const float* __restrict__ Wih1, const float* __restrict__ Whh1,
                  const float* __restrict__ bih1, const float* __restrict__ bhh1,
                  const float* __restrict__ Wh1,  const float* __restrict__ bh1,
                  const float* __restrict__ Wh2,  const float* __restrict__ bh2,
                  float* __restrict__ out)
{
    // [h][b] layout: one ds_read_b128 broadcast serves all 4 batch lanes
    __shared__ __align__(16) float xs[T_LEN][4][B_TILE];   // 32 KB, [t][f][b]
    __shared__ __align__(16) float h1s[HID][B_TILE];       // 1 KB
    __shared__ __align__(16) float h2s[HID][B_TILE];       // 1 KB
    __shared__ __align__(16) float g0s[NG][B_TILE];        // 4 KB
    __shared__ __align__(16) float g1s[NG][B_TILE];        // 4 KB
    __shared__ __align__(16) float hds[32][B_TILE];

    const int tid   = threadIdx.x;
    const int wave  = tid >> 6;
    const int lane  = tid & 63;
    const int p     = lane >> 5;        // half-row index (0: h[0:32), 1: h[32:64))
    const int g     = wave * 32 + (lane & 31);   // gate row 0..255
    const int gtype = wave >> 1;        // 0:i 1:f 2:g(tanh) 3:o  (wave-uniform)
    const int b0    = blockIdx.x * B_TILE;
    const int j     = tid & 63;         // update-phase hidden channel
    const int bb    = (tid >> 6) & 3;   // update-phase batch lane (tid<256 only)

    // ---- per-thread HALF-row weights: 24 named f4 regs (96 VGPRs) ----
    const f4* q0 = (const f4*)(Whh0 + g * HID + p * 32);
    const f4* q1 = (const f4*)(Wih1 + g * HID + p * 32);
    const f4* q2 = (const f4*)(Whh1 + g * HID + p * 32);
#define D0(k) f4 a0_##k = q0[k];
#define D1(k) f4 a1_##k = q1[k];
#define D2(k) f4 a2_##k = q2[k];
    REP8(D0)
    REP8(D1)
    REP8(D2)

    f4 wih0r = *(const f4*)(Wih0 + g * 4);
    if (p) wih0r = (f4){0.f, 0.f, 0.f, 0.f};           // x-part counted once
    const float b0eff = p ? 0.0f : (bih0[g] + bhh0[g]); // bias counted once
    const float b1eff = p ? 0.0f : (bih1[g] + bhh1[g]);

    // ---- stage x slice: x[b0+xb][t][f] -> xs[t][f][xb] ----
    {
        const f4* xg = (const f4*)(x + (size_t)b0 * T_LEN * 4);
        for (int i = tid; i < B_TILE * T_LEN; i += NTHR) {
            const int xb = i >> 9;          // /T_LEN
            const int t  = i & (T_LEN - 1);
            f4 v = xg[i];
#pragma unroll
            for (int f = 0; f < 4; ++f) xs[t][f][xb] = v[f];
        }
    }
    if (tid < 256) {                       // HID*B_TILE == 256
        ((float*)h1s)[tid] = 0.0f;
        ((float*)h2s)[tid] = 0.0f;
    }
    float c1 = 0.0f, c2 = 0.0f;

    __syncthreads();

    // broadcast f4 pointers into this thread's half of h
    const f4* h1p = ((const f4*)h1s) + p * 32;   // h1p[i] = h1s[p*32+i][0..3]
    const f4* h2p = ((const f4*)h2s) + p * 32;

    for (int t = 0; t < T_LEN; ++t) {
        // ---- layer 0 half-matvec + lane-pair combine ----
        {
            f4 acc = {b0eff, b0eff, b0eff, b0eff};
            {
                f4 xv0 = *(const f4*)&xs[t][0][0];
                f4 xv1 = *(const f4*)&xs[t][1][0];
                f4 xv2 = *(const f4*)&xs[t][2][0];
                f4 xv3 = *(const f4*)&xs[t][3][0];
                acc += xv0 * wih0r[0];
                acc += xv1 * wih0r[1];
                acc += xv2 * wih0r[2];
                acc += xv3 * wih0r[3];
            }
#define M0(k) { const f4 hv0 = h1p[4*(k)+0], hv1 = h1p[4*(k)+1], \
                         hv2 = h1p[4*(k)+2], hv3 = h1p[4*(k)+3]; \
                acc += hv0 * a0_##k[0]; acc += hv1 * a0_##k[1];  \
                acc += hv2 * a0_##k[2]; acc += hv3 * a0_##k[3]; }
            REP8(M0)
#pragma unroll
            for (int c = 0; c < 4; ++c) acc[c] += __shfl_xor(acc[c], 32);
            f4 av;
            if (gtype == 2) {
#pragma unroll
                for (int i = 0; i < 4; ++i) av[i] = tanh_f(acc[i]);
            } else {
#pragma unroll
                for (int i = 0; i < 4; ++i) av[i] = sigm(acc[i]);
            }
            if (p == 0) *(f4*)&g0s[g][0] = av;
        }
        __syncthreads();
        // ---- layer 0 elementwise update (waves 0-3) ----
        if (tid < 256) {
            float ig = g0s[j][bb], fg = g0s[64 + j][bb], gg = g0s[128 + j][bb], og = g0s[192 + j][bb];
            c1 = fg * c1 + ig * gg;
            h1s[j][bb] = og * tanh_f(c1);
        }
        __syncthreads();
        // ---- layer 1 half-matvec (h1_t and h2_{t-1}) + combine ----
        {
            f4 acc = {b1eff, b1eff, b1eff, b1eff};
#define M1(k) { const f4 hv0 = h1p[4*(k)+0], hv1 = h1p[4*(k)+1], \
                         hv2 = h1p[4*(k)+2], hv3 = h1p[4*(k)+3]; \
                acc += hv0 * a1_##k[0]; acc += hv1 * a1_##k[1];  \
                acc += hv2 * a1_##k[2]; acc += hv3 * a1_##k[3]; }
            REP8(M1)
#define M2(k) { const f4 hv0 = h2p[4*(k)+0], hv1 = h2p[4*(k)+1], \
                         hv2 = h2p[4*(k)+2], hv3 = h2p[4*(k)+3]; \
                acc += hv0 * a2_##k[0]; acc += hv1 * a2_##k[1];  \
                acc += hv2 * a2_##k[2]; acc += hv3 * a2_##k[3]; }
            REP8(M2)
#pragma unroll
            for (int c = 0; c < 4; ++c) acc[c] += __shfl_xor(acc[c], 32);
            f4 av;
            if (gtype == 2) {
#pragma unroll
                for (int i = 0; i < 4; ++i) av[i] = tanh_f(acc[i]);
            } else {
#pragma unroll
                for (int i = 0; i < 4; ++i) av[i] = sigm(acc[i]);
            }
            if (p == 0) *(f4*)&g1s[g][0] = av;
        }
        __syncthreads();
        // ---- layer 1 elementwise update (waves 0-3).  Next-iter MV0 touches
        // only xs/h1s/g0s, disjoint from h2s/g1s -> 3 barriers/step suffice ----
        if (tid < 256) {
            float ig = g1s[j][bb], fg = g1s[64 + j][bb], gg = g1s[128 + j][bb], og = g1s[192 + j][bb];
            c2 = fg * c2 + ig * gg;
            h2s[j][bb] = og * tanh_f(c2);
        }
    }
    __syncthreads();

    // ---- head: Linear(64,32) + ReLU + Linear(32,1) ----
    if (tid < 128) {
        const int k = tid & 31, b = tid >> 5;
        float a = bh1[k];
#pragma unroll 8
        for (int jj = 0; jj < HID; ++jj) a += Wh1[k * HID + jj] * h2s[jj][b];
        hds[k][b] = fmaxf(a, 0.0f);
    }
    __syncthreads();
    if (tid < B_TILE) {
        float a = bh2[0];
#pragma unroll
        for (int k = 0; k < 32; ++k) a += Wh2[k] * hds[k][tid];
        out[b0 + tid] = a;
    }
}

extern "C" void kernel_launch(void* const* d_in, const int* in_sizes, int n_in,
                              void* d_out, int out_size, void* d_ws, size_t ws_size,
                              hipStream_t stream) {
    const float* x    = (const float*)d_in[0];
    const float* Wih0 = (const float*)d_in[1];
    const float* Whh0 = (const float*)d_in[2];
    const float* bih0 = (const float*)d_in[3];
    const float* bhh0 = (const float*)d_in[4];
    const float* Wih1 = (const float*)d_in[5];
    const float* Whh1 = (const float*)d_in[6];
    const float* bih1 = (const float*)d_in[7];
    const float* bhh1 = (const float*)d_in[8];
    const float* Wh1  = (const float*)d_in[9];
    const float* bh1  = (const float*)d_in[10];
    const float* Wh2  = (const float*)d_in[11];
    const float* bh2  = (const float*)d_in[12];
    float* out = (float*)d_out;

    const int B = out_size;              // 2048
    const int grid = B / B_TILE;         // 512 blocks

    lstm2_kernel<<<grid, NTHR, 0, stream>>>(x, Wih0, Whh0, bih0, bhh0,
                                            Wih1, Whh1, bih1, bhh1,
                                            Wh1, bh1, Wh2, bh2, out);
}

// Round 14
// 10507.876 us; speedup vs baseline: 2.9717x; 2.9717x over previous
//
#include <hip/hip_runtime.h>

#define T_LEN 512
#define HID   64
#define NG    256   // 4*HID gate rows
#define B_TILE 4
#define NTHR  512
#define WS0_STRIDE 67   // bank = (3g+k)%32: 32 distinct banks across g; p-pairs 2-way (free)

typedef float f4 __attribute__((ext_vector_type(4)));

__device__ __forceinline__ float sigm(float x)  { return 1.0f / (1.0f + __expf(-x)); }
__device__ __forceinline__ float tanh_f(float x){ float e = __expf(2.0f * x); return 1.0f - 2.0f / (e + 1.0f); }

#define REP8(M) M(0) M(1) M(2) M(3) M(4) M(5) M(6) M(7)

// Keep-live pin: harmless when demand<=grant, prevents sink/spill choice
// from picking the weights.
#define PINV(v) asm volatile("" : "+v"((v)[0]), "+v"((v)[1]), "+v"((v)[2]), "+v"((v)[3]))

// r1-r11 lesson: allocator grants a FIXED budget (512-thr block -> 128 VGPR)
// no matter what attributes say, and spills the overflow weights to scratch
// (r8: WRITE 230MB = one-time spill store, FETCH 57GB = per-step re-reads
// thrashing L3). Fix: demand <= 128 by construction. Only Wih1+Whh1 half-rows
// live in regs (16 f4 = 64 VGPRs, pinned); Whh0 lives in LDS (stride-67 rows,
// conflict-free b32 reads). Demand ~105-120 < 128 -> nothing to spill.
__global__ __launch_bounds__(NTHR, 2)
void lstm2_kernel(const float* __restrict__ x,
                  const float* __restrict__ Wih0, const float* __restrict__ Whh0,
                  const float* __restrict__ bih0, const float* __restrict__ bhh0,
                  const float* __restrict__ Wih1, const float* __restrict__ Whh1,
                  const float* __restrict__ bih1, const float* __restrict__ bhh1,
                  const float* __restrict__ Wh1,  const float* __restrict__ bh1,
                  const float* __restrict__ Wh2,  const float* __restrict__ bh2,
                  float* __restrict__ out)
{
    __shared__ __align__(16) float xs[T_LEN][4][B_TILE];     // 32 KB [t][f][b]
    __shared__ __align__(16) float ws0[NG * WS0_STRIDE];     // 68.6 KB Whh0
    __shared__ __align__(16) float h1s[HID][B_TILE];         // 1 KB
    __shared__ __align__(16) float h2s[HID][B_TILE];         // 1 KB
    __shared__ __align__(16) float g0s[NG][B_TILE];          // 4 KB
    __shared__ __align__(16) float g1s[NG][B_TILE];          // 4 KB
    __shared__ __align__(16) float hds[32][B_TILE];          // total ~112 KB -> 1 block/CU

    const int tid   = threadIdx.x;
    const int wave  = tid >> 6;
    const int lane  = tid & 63;
    const int p     = lane >> 5;        // half-row index (0: h[0:32), 1: h[32:64))
    const int g     = wave * 32 + (lane & 31);   // gate row 0..255
    const int gtype = wave >> 1;        // 0:i 1:f 2:g(tanh) 3:o  (wave-uniform)
    const int b0    = blockIdx.x * B_TILE;
    const int j     = tid & 63;         // update-phase hidden channel
    const int bb    = (tid >> 6) & 3;   // update-phase batch lane (tid<256 only)

    // ---- register weights: Wih1 + Whh1 half-rows, 16 named f4 (64 VGPRs) ----
    const f4* q1 = (const f4*)(Wih1 + g * HID + p * 32);
    const f4* q2 = (const f4*)(Whh1 + g * HID + p * 32);
#define D1(k) f4 a1_##k = q1[k];
#define D2(k) f4 a2_##k = q2[k];
    REP8(D1)
    REP8(D2)

    f4 wih0r = *(const f4*)(Wih0 + g * 4);
    if (p) wih0r = (f4){0.f, 0.f, 0.f, 0.f};           // x-part counted once
    float b0eff = p ? 0.0f : (bih0[g] + bhh0[g]);       // bias counted once
    float b1eff = p ? 0.0f : (bih1[g] + bhh1[g]);

#define P1(k) PINV(a1_##k);
#define P2(k) PINV(a2_##k);
    REP8(P1)
    REP8(P2)
    PINV(wih0r);
    asm volatile("" : "+v"(b0eff), "+v"(b1eff));

    // ---- stage Whh0 -> LDS (stride 67) ----
    {
        const f4* wg = (const f4*)Whh0;          // 4096 f4
        for (int i = tid; i < NG * HID / 4; i += NTHR) {
            f4 v = wg[i];
            const int row = i >> 4;
            const int kq  = (i & 15) << 2;
            float* d = &ws0[row * WS0_STRIDE + kq];
            d[0] = v[0]; d[1] = v[1]; d[2] = v[2]; d[3] = v[3];
        }
    }
    // ---- stage x slice: x[b0+xb][t][f] -> xs[t][f][xb] ----
    {
        const f4* xg = (const f4*)(x + (size_t)b0 * T_LEN * 4);
        for (int i = tid; i < B_TILE * T_LEN; i += NTHR) {
            const int xb = i >> 9;          // /T_LEN
            const int t  = i & (T_LEN - 1);
            f4 v = xg[i];
#pragma unroll
            for (int f = 0; f < 4; ++f) xs[t][f][xb] = v[f];
        }
    }
    if (tid < 256) {                       // HID*B_TILE == 256
        ((float*)h1s)[tid] = 0.0f;
        ((float*)h2s)[tid] = 0.0f;
    }
    float c1 = 0.0f, c2 = 0.0f;

    __syncthreads();

    const f4* h1p = ((const f4*)h1s) + p * 32;   // h1p[k] = h1s[p*32+k][0..3] (broadcast)
    const f4* h2p = ((const f4*)h2s) + p * 32;
    const float* wr = ws0 + g * WS0_STRIDE + p * 32;   // this thread's Whh0 half-row

    for (int t = 0; t < T_LEN; ++t) {
        // ---- layer 0 half-matvec (Whh0 from LDS) + lane-pair combine ----
        {
            f4 acc = {b0eff, b0eff, b0eff, b0eff};
            {
                f4 xv0 = *(const f4*)&xs[t][0][0];
                f4 xv1 = *(const f4*)&xs[t][1][0];
                f4 xv2 = *(const f4*)&xs[t][2][0];
                f4 xv3 = *(const f4*)&xs[t][3][0];
                acc += xv0 * wih0r[0];
                acc += xv1 * wih0r[1];
                acc += xv2 * wih0r[2];
                acc += xv3 * wih0r[3];
            }
#pragma unroll
            for (int k = 0; k < 32; ++k)
                acc += h1p[k] * wr[k];      // b128 broadcast * b32 scalar weight
#pragma unroll
            for (int c = 0; c < 4; ++c) acc[c] += __shfl_xor(acc[c], 32);
            f4 av;
            if (gtype == 2) {
#pragma unroll
                for (int i = 0; i < 4; ++i) av[i] = tanh_f(acc[i]);
            } else {
#pragma unroll
                for (int i = 0; i < 4; ++i) av[i] = sigm(acc[i]);
            }
            if (p == 0) *(f4*)&g0s[g][0] = av;
        }
        __syncthreads();
        // ---- layer 0 elementwise update (waves 0-3) ----
        if (tid < 256) {
            float ig = g0s[j][bb], fg = g0s[64 + j][bb], gg = g0s[128 + j][bb], og = g0s[192 + j][bb];
            c1 = fg * c1 + ig * gg;
            h1s[j][bb] = og * tanh_f(c1);
        }
        __syncthreads();
        // ---- layer 1 half-matvec (register weights) + combine ----
        {
            f4 acc = {b1eff, b1eff, b1eff, b1eff};
#define M1(k) { const f4 hv0 = h1p[4*(k)+0], hv1 = h1p[4*(k)+1], \
                         hv2 = h1p[4*(k)+2], hv3 = h1p[4*(k)+3]; \
                acc += hv0 * a1_##k[0]; acc += hv1 * a1_##k[1];  \
                acc += hv2 * a1_##k[2]; acc += hv3 * a1_##k[3]; }
            REP8(M1)
#define M2(k) { const f4 hv0 = h2p[4*(k)+0], hv1 = h2p[4*(k)+1], \
                         hv2 = h2p[4*(k)+2], hv3 = h2p[4*(k)+3]; \
                acc += hv0 * a2_##k[0]; acc += hv1 * a2_##k[1];  \
                acc += hv2 * a2_##k[2]; acc += hv3 * a2_##k[3]; }
            REP8(M2)
#pragma unroll
            for (int c = 0; c < 4; ++c) acc[c] += __shfl_xor(acc[c], 32);
            f4 av;
            if (gtype == 2) {
#pragma unroll
                for (int i = 0; i < 4; ++i) av[i] = tanh_f(acc[i]);
            } else {
#pragma unroll
                for (int i = 0; i < 4; ++i) av[i] = sigm(acc[i]);
            }
            if (p == 0) *(f4*)&g1s[g][0] = av;
        }
        __syncthreads();
        // ---- layer 1 elementwise update.  Next-iter L0 touches only
        // xs/ws0/h1s/g0s, disjoint from h2s/g1s -> 3 barriers/step ----
        if (tid < 256) {
            float ig = g1s[j][bb], fg = g1s[64 + j][bb], gg = g1s[128 + j][bb], og = g1s[192 + j][bb];
            c2 = fg * c2 + ig * gg;
            h2s[j][bb] = og * tanh_f(c2);
        }
    }
    __syncthreads();

    // ---- head: Linear(64,32) + ReLU + Linear(32,1) ----
    if (tid < 128) {
        const int k = tid & 31, b = tid >> 5;
        float a = bh1[k];
#pragma unroll 8
        for (int jj = 0; jj < HID; ++jj) a += Wh1[k * HID + jj] * h2s[jj][b];
        hds[k][b] = fmaxf(a, 0.0f);
    }
    __syncthreads();
    if (tid < B_TILE) {
        float a = bh2[0];
#pragma unroll
        for (int k = 0; k < 32; ++k) a += Wh2[k] * hds[k][tid];
        out[b0 + tid] = a;
    }
}

extern "C" void kernel_launch(void* const* d_in, const int* in_sizes, int n_in,
                              void* d_out, int out_size, void* d_ws, size_t ws_size,
                              hipStream_t stream) {
    const float* x    = (const float*)d_in[0];
    const float* Wih0 = (const float*)d_in[1];
    const float* Whh0 = (const float*)d_in[2];
    const float* bih0 = (const float*)d_in[3];
    const float* bhh0 = (const float*)d_in[4];
    const float* Wih1 = (const float*)d_in[5];
    const float* Whh1 = (const float*)d_in[6];
    const float* bih1 = (const float*)d_in[7];
    const float* bhh1 = (const float*)d_in[8];
    const float* Wh1  = (const float*)d_in[9];
    const float* bh1  = (const float*)d_in[10];
    const float* Wh2  = (const float*)d_in[11];
    const float* bh2  = (const float*)d_in[12];
    float* out = (float*)d_out;

    const int B = out_size;              // 2048
    const int grid = B / B_TILE;         // 512 blocks, 1/CU resident, 2 rounds

    lstm2_kernel<<<grid, NTHR, 0, stream>>>(x, Wih0, Whh0, bih0, bhh0,
                                            Wih1, Whh1, bih1, bhh1,
                                            Wh1, bh1, Wh2, bh2, out);
}